// Round 2
// baseline (334.997 us; speedup 1.0000x reference)
//
#include <hip/hip_runtime.h>

#define BATCH 128
#define NCELL 2048
#define OWN 512             // cells owned per block
#define HALO 256            // >= stepnum-2 = 254
#define WIDTH 1024          // OWN + 2*HALO
#define NTHREADS 256        // WIDTH / 4 cells per thread

typedef float f32x4 __attribute__((ext_vector_type(4)));

// flux(u) expanded to a polynomial (beta = 0.1):
// f(u)  = 1.5u + 0.00625u^2 - 0.5166666...u^3 + 0.0125u^4 - 0.00208333...u^6
// f'(u) = 1.5 + 0.0125u - 1.55u^2 + 0.05u^3 - 0.0125u^5
__device__ __forceinline__ float flux_h(float u, float u2) {
    float h = fmaf(u2, -0.0020833333333333333f, 0.0125f);
    h = fmaf(u, h, -0.5166666666666667f);
    h = fmaf(u, h, 0.00625f);
    h = fmaf(u, h, 1.5f);
    return u * h;
}
__device__ __forceinline__ float aprime_h(float u, float u2) {
    float h = fmaf(u2, -0.0125f, 0.05f);
    h = fmaf(u, h, -1.55f);
    h = fmaf(u, h, 0.0125f);
    h = fmaf(u, h, 1.5f);
    return fabsf(h);
}

// Trapezoid time-tiling: 4 blocks per batch row (grid=512 -> 2 blocks/CU so
// independent barrier groups overlap). Each block owns 512 cells and
// redundantly computes a halo shrinking 1 cell/step (max 254). No inter-block
// communication. Thread t holds 4 contiguous cells in registers; per step:
// 1 ds_write_b128, 1 barrier, 2 ds_read_b32, stencil in registers, coalesced
// nontemporal float4 store of the owned trajectory slice.
//
// KEY change vs the 327.9 µs baseline: __syncthreads() made hipcc emit
// "s_waitcnt vmcnt(0) lgkmcnt(0)" before s_barrier, draining the per-step
// global trajectory store 255 times (HBM store latency exposed serially).
// We only need LDS ordering across the barrier, so use a raw
// "s_waitcnt lgkmcnt(0); s_barrier" — global stores stay in flight.
// Double-buffered ubuf makes one barrier per step sufficient: writes to
// buffer X at step s+2 are ordered after barrier(s+1), which is after all
// reads of X at step s.
__global__ __launch_bounds__(NTHREADS)
void VariantCoeLinear1d_kernel(const float* __restrict__ init,
                               const int* __restrict__ stepnum_p,
                               float* __restrict__ out) {
    __shared__ float ubuf[2][WIDTH];

    const int b = blockIdx.x;
    const int row = b >> 2;
    const int q = b & 3;
    const int t = threadIdx.x;
    const int S = *stepnum_p;
    const float c = 0.4096f;             // float(DT/DX)

    const int ownedLo = q * OWN;
    const int ownedHi = ownedLo + OWN - 1;
    const int base = ownedLo - HALO;     // global index of LDS cell 0
    const int li = t << 2;               // my first LDS cell
    const int g0 = base + li;            // my first global cell

    // ---- load init (clamped at row edges; out-of-row halo cells hold the
    //      clamped edge value and are provably never used as real inputs) ----
    const float* rin = init + (size_t)row * NCELL;
    float u0, u1, u2, u3;
    if (g0 >= 0 && g0 + 3 < NCELL) {
        float4 v = *(const float4*)(rin + g0);
        u0 = v.x; u1 = v.y; u2 = v.z; u3 = v.w;
    } else {
        u0 = rin[min(max(g0 + 0, 0), NCELL - 1)];
        u1 = rin[min(max(g0 + 1, 0), NCELL - 1)];
        u2 = rin[min(max(g0 + 2, 0), NCELL - 1)];
        u3 = rin[min(max(g0 + 3, 0), NCELL - 1)];
    }

    const bool owned = (t >= HALO / 4) && (t < (HALO + OWN) / 4); // 64..191
    float* op = out + (size_t)row * NCELL + g0;   // step-0 output address
    if (owned) {
        __builtin_nontemporal_store((f32x4){u0, u1, u2, u3}, (f32x4*)op);
    }

    int cur = 0;
    for (int s = 1; s < S; ++s) {
        float* ub = ubuf[cur];
        *(float4*)&ub[li] = make_float4(u0, u1, u2, u3);
        // LDS-only fence + barrier (do NOT drain vmcnt: trajectory stores
        // from previous steps must stay in flight).
        asm volatile("s_waitcnt lgkmcnt(0)\n\ts_barrier" ::: "memory");

        const int rem = (S - 1) - s;               // remaining steps after s
        const int lo = max(ownedLo - rem, 0);      // active region this step
        const int hi = min(ownedHi + rem, NCELL - 1);
        op += (size_t)BATCH * NCELL;

        if (g0 + 3 >= lo && g0 <= hi) {
            const float ulm = ub[max(li - 1, 0)];
            const float ulp = ub[min(li + 4, WIDTH - 1)];
            float ul[6] = {ulm, u0, u1, u2, u3, ulp};
            float f[6], a[6];
#pragma unroll
            for (int j = 0; j < 6; ++j) {
                const float uu = ul[j], uu2 = uu * uu;
                f[j] = flux_h(uu, uu2);
                a[j] = aprime_h(uu, uu2);
            }
            float fh[5];
#pragma unroll
            for (int j = 0; j < 5; ++j) {
                fh[j] = 0.5f * (f[j] + f[j + 1])
                      - 0.5f * fmaxf(a[j], a[j + 1]) * (ul[j + 1] - ul[j]);
            }
            float un[4];
#pragma unroll
            for (int i = 0; i < 4; ++i) {
                un[i] = ul[i + 1] - c * (fh[i + 1] - fh[i]);
                const int g = g0 + i;
                un[i] = (g >= lo && g <= hi) ? un[i] : ul[i + 1];
            }
            // Outflow BC (only row-edge cells):
            if (g0 == 0) un[0] = un[1];
            if (g0 + 3 == NCELL - 1) un[3] = un[2];
            u0 = un[0]; u1 = un[1]; u2 = un[2]; u3 = un[3];

            if (owned) {
                __builtin_nontemporal_store((f32x4){u0, u1, u2, u3}, (f32x4*)op);
            }
        }
        cur ^= 1;
    }
}

extern "C" void kernel_launch(void* const* d_in, const int* in_sizes, int n_in,
                              void* d_out, int out_size, void* d_ws, size_t ws_size,
                              hipStream_t stream) {
    const float* init = (const float*)d_in[0];
    const int* stepnum = (const int*)d_in[1];
    float* out = (float*)d_out;

    dim3 grid(BATCH * 4);   // 4 trapezoid blocks per row -> 2 blocks/CU
    dim3 block(NTHREADS);
    VariantCoeLinear1d_kernel<<<grid, block, 0, stream>>>(init, stepnum, out);
}